// Round 17
// baseline (60.869 us; speedup 1.0000x reference)
//
#include <hip/hip_runtime.h>
#include <hip/hip_fp16.h>
#include <cstdint>

#define EPSF 1e-5f

typedef __attribute__((ext_vector_type(8))) _Float16  f16x8;
typedef __attribute__((ext_vector_type(4))) float     f32x4;
typedef __attribute__((ext_vector_type(4))) unsigned int uint32x4;
typedef __attribute__((ext_vector_type(2))) unsigned int uint32x2;

// ---- workspace layout ----
#define WS_B0 0
#define WS_BC 64
#define WS_BF 128
// f16 A-fragments: wsA1 @4096 (24*512), wsA2 @28672 (16*512), wsA3 @45056 (4*512, conv K=32)

__device__ __forceinline__ unsigned short f2h(float f) {
    __half h = __float2half(f);              // RNE
    return *reinterpret_cast<unsigned short*>(&h);
}

// f32 pair -> f16 pair (RTZ), single instruction
__device__ __forceinline__ unsigned cvtpk_h(float lo, float hi) {
    unsigned r;
    asm("v_cvt_pkrtz_f16_f32 %0, %1, %2" : "=v"(r) : "v"(lo), "v"(hi));
    return r;
}

// ---- packed f16 VOP3P helpers (TRUE dual-rate on CDNA; op_sel folds broadcasts) ----
__device__ __forceinline__ unsigned pkfma(unsigned a, unsigned b, unsigned c) {
    unsigned d; asm("v_pk_fma_f16 %0, %1, %2, %3" : "=v"(d) : "v"(a), "v"(b), "v"(c)); return d;
}
__device__ __forceinline__ unsigned pkfma_lo(unsigned a, unsigned b, unsigned c) {  // bcast a.lo
    unsigned d; asm("v_pk_fma_f16 %0, %1, %2, %3 op_sel_hi:[0,1,1]" : "=v"(d) : "v"(a), "v"(b), "v"(c)); return d;
}
__device__ __forceinline__ unsigned pkfma_hi(unsigned a, unsigned b, unsigned c) {  // bcast a.hi
    unsigned d; asm("v_pk_fma_f16 %0, %1, %2, %3 op_sel:[1,0,0]" : "=v"(d) : "v"(a), "v"(b), "v"(c)); return d;
}
__device__ __forceinline__ unsigned pkmul(unsigned a, unsigned b) {
    unsigned d; asm("v_pk_mul_f16 %0, %1, %2" : "=v"(d) : "v"(a), "v"(b)); return d;
}
__device__ __forceinline__ unsigned pkmul_lo(unsigned a, unsigned b) {
    unsigned d; asm("v_pk_mul_f16 %0, %1, %2 op_sel_hi:[0,1]" : "=v"(d) : "v"(a), "v"(b)); return d;
}
__device__ __forceinline__ unsigned pkmul_hi(unsigned a, unsigned b) {
    unsigned d; asm("v_pk_mul_f16 %0, %1, %2 op_sel:[1,0]" : "=v"(d) : "v"(a), "v"(b)); return d;
}
__device__ __forceinline__ unsigned pkadd(unsigned a, unsigned b) {
    unsigned d; asm("v_pk_add_f16 %0, %1, %2" : "=v"(d) : "v"(a), "v"(b)); return d;
}

#define C_HALF2  0x38003800u   // (0.5h, 0.5h)
#define C_THIRD2 0x35553555u   // (1/3 h, 1/3 h)

// ---------------- prep: fold BNs, collapse W_ps@{W_ssig,W_tsig}, pack MFMA A-frags (f16) ----------------
__global__ __launch_bounds__(64) void stem_prep(
    const float* __restrict__ W_ssig, const float* __restrict__ b_ssig,
    const float* __restrict__ W_tsig, const float* __restrict__ b_tsig,
    const float* __restrict__ W_raw,  const float* __restrict__ b_raw,
    const float* __restrict__ W_ps,   const float* __restrict__ b_ps,
    const float* __restrict__ W_fu,   const float* __restrict__ b_fu,
    const float* __restrict__ g_raw, const float* __restrict__ be_raw,
    const float* __restrict__ m_raw, const float* __restrict__ v_raw,
    const float* __restrict__ g_ps,  const float* __restrict__ be_ps,
    const float* __restrict__ m_ps,  const float* __restrict__ v_ps,
    const float* __restrict__ g_fu,  const float* __restrict__ be_fu,
    const float* __restrict__ m_fu,  const float* __restrict__ v_fu,
    float* __restrict__ wsf, unsigned short* __restrict__ wsA1,
    unsigned short* __restrict__ wsA2, unsigned short* __restrict__ wsA3)
{
    const int l = threadIdx.x;         // 0..63
    const int f = blockIdx.x;
    if (f < 24) {
        const int h = f / 12, rem = f % 12, s = rem / 4, to = rem % 4;
        const int o = to*16 + (l & 15);
        const float sps = g_ps[o] / sqrtf(v_ps[o] + EPSF);
        const float* wp  = W_ps + o*128 + 64*h;
        const float* wsg = h ? W_tsig : W_ssig;
        for (int b = 0; b < 8; ++b) {
            const int k = s*32 + ((l >> 4) * 8) + b;
            float v = 0.f;
            if (k < 84) {
                float acc = 0.f;
                for (int c = 0; c < 64; ++c) acc = fmaf(wp[c], wsg[c*84 + k], acc);
                v = acc * sps;
            }
            wsA1[f*512 + l*8 + b] = f2h(v);
        }
    } else if (f < 40) {
        const int q = f - 24, s = q / 4, to = q % 4;
        const int o = to*16 + (l & 15);
        const float sfu = g_fu[o] / sqrtf(v_fu[o] + EPSF);
        for (int b = 0; b < 8; ++b) {
            const int c = s*32 + ((l >> 4) * 8) + b;
            wsA2[q*512 + l*8 + b] = f2h(W_fu[o*128 + c] * sfu);
        }
    } else if (f == 40) {
        const int o = l;
        const float sps = g_ps[o] / sqrtf(v_ps[o] + EPSF);
        float acc = b_ps[o] - m_ps[o];
        for (int c = 0; c < 64; ++c) {
            acc = fmaf(W_ps[o*128 + c],      b_ssig[c], acc);
            acc = fmaf(W_ps[o*128 + 64 + c], b_tsig[c], acc);
        }
        wsf[WS_B0 + o] = acc * sps + be_ps[o];
        const float sraw = g_raw[o] / sqrtf(v_raw[o] + EPSF);
        wsf[WS_BC + o] = (b_raw[o] - m_raw[o]) * sraw + be_raw[o];
        const float sfu = g_fu[o] / sqrtf(v_fu[o] + EPSF);
        wsf[WS_BF + o] = (b_fu[o] - m_fu[o]) * sfu + be_fu[o];
    } else {
        const int to = f - 41;
        const int o = to*16 + (l & 15);
        const float sraw = g_raw[o] / sqrtf(v_raw[o] + EPSF);
        for (int b = 0; b < 8; ++b) {
            const int k = ((l >> 4) * 8) + b;
            wsA3[to*512 + l*8 + b] = (k < 9) ? f2h(W_raw[o*9 + k] * sraw) : (unsigned short)0;
        }
    }
}

// ---- packed-f16 factored sig step (56 pk insts). S[42]: S1=S[0..1], S2=S[2..9], S3=S[10..41].
__device__ __forceinline__ void sig_step_h(unsigned* __restrict__ S, unsigned d01, unsigned d23)
{
    const unsigned dh0 = pkmul(C_HALF2, d01), dh1 = pkmul(C_HALF2, d23);
    const unsigned fv0 = pkfma(d01, C_THIRD2, S[0]);
    const unsigned fv1 = pkfma(d23, C_THIRD2, S[1]);
    unsigned h[8];                                // h[i*2+p], OLD S2
    h[0] = pkfma_lo(fv0, dh0, S[2]); h[1] = pkfma_lo(fv0, dh1, S[3]);
    h[2] = pkfma_hi(fv0, dh0, S[4]); h[3] = pkfma_hi(fv0, dh1, S[5]);
    h[4] = pkfma_lo(fv1, dh0, S[6]); h[5] = pkfma_lo(fv1, dh1, S[7]);
    h[6] = pkfma_hi(fv1, dh0, S[8]); h[7] = pkfma_hi(fv1, dh1, S[9]);
#pragma unroll
    for (int i = 0; i < 4; ++i) {
#pragma unroll
        for (int j = 0; j < 4; ++j) {
            const int hr = i*2 + (j>>1);
            const int base = 10 + (i*4+j)*2;
            if (j & 1) { S[base]   = pkfma_hi(h[hr], d01, S[base]);
                         S[base+1] = pkfma_hi(h[hr], d23, S[base+1]); }
            else       { S[base]   = pkfma_lo(h[hr], d01, S[base]);
                         S[base+1] = pkfma_lo(h[hr], d23, S[base+1]); }
        }
    }
    const unsigned q0 = pkadd(S[0], dh0), q1 = pkadd(S[1], dh1);   // OLD S1
    S[2] = pkfma_lo(q0, d01, S[2]); S[3] = pkfma_lo(q0, d23, S[3]);
    S[4] = pkfma_hi(q0, d01, S[4]); S[5] = pkfma_hi(q0, d23, S[5]);
    S[6] = pkfma_lo(q1, d01, S[6]); S[7] = pkfma_lo(q1, d23, S[7]);
    S[8] = pkfma_hi(q1, d01, S[8]); S[9] = pkfma_hi(q1, d23, S[9]);
    S[0] = pkadd(S[0], d01); S[1] = pkadd(S[1], d23);
}

// first step from zero state (d3==0 in d23.hi): S1=d, S2=dh_i*d_j, S3=(d_i/3)*S2[jk]
__device__ __forceinline__ void sig_init_h(unsigned* __restrict__ S, unsigned d01, unsigned d23)
{
    S[0] = d01; S[1] = d23;
    const unsigned dh0 = pkmul(C_HALF2, d01), dh1 = pkmul(C_HALF2, d23);
    S[2] = pkmul_lo(dh0, d01); S[3] = pkmul_lo(dh0, d23);
    S[4] = pkmul_hi(dh0, d01); S[5] = pkmul_hi(dh0, d23);
    S[6] = pkmul_lo(dh1, d01); S[7] = pkmul_lo(dh1, d23);
    S[8] = pkmul_hi(dh1, d01); S[9] = pkmul_hi(dh1, d23);
    const unsigned td0 = pkmul(C_THIRD2, d01), td1 = pkmul(C_THIRD2, d23);
#pragma unroll
    for (int i = 0; i < 4; ++i) {
        const unsigned tdr = (i < 2) ? td0 : td1;
#pragma unroll
        for (int j = 0; j < 4; ++j) {
            const int base = 10 + (i*4+j)*2;
            if (i & 1) { S[base]   = pkmul_hi(tdr, S[2+j*2]);
                         S[base+1] = pkmul_hi(tdr, S[2+j*2+1]); }
            else       { S[base]   = pkmul_lo(tdr, S[2+j*2]);
                         S[base+1] = pkmul_lo(tdr, S[2+j*2+1]); }
        }
    }
}

// grid: (4 t-chunks, 64 j, 32 b); block 64 = 1 wave. k-major LDS: slot s at byte
// s*1024 + row*16; 11 slots = 11264 B (slot-11 reads REMAPPED to slot 8: their A
// fragments are exactly zero (k>=84), and 0 x finite = 0 -- k-permutation-safe).
// Conv xv uses only slots 8,9 (lg=2,3 B-reads remap to 8,9; A=0 for k>=16).
// GEMM1a MFMAs are ISSUED BEFORE sigma_t's VALU so the 340 pk-ops execute in the
// MFMA pipe's shadow (within-wave co-issue). __syncthreads() at every LDS
// phase boundary (rounds 14/15: cheaper fences broke correctness; reverted).
__global__ __launch_bounds__(64, 3) void stem_main(
    const float* __restrict__ x, const int* __restrict__ path,
    const float* __restrict__ wsf, const unsigned short* __restrict__ wsA1,
    const unsigned short* __restrict__ wsA2, const unsigned short* __restrict__ wsA3,
    float* __restrict__ out)
{
    __shared__ char sb[11 * 1024];
    const int l  = threadIdx.x;                  // lane
    const int t  = blockIdx.x * 64 + l;          // global t for this thread's column
    const int j  = blockIdx.y;
    const int b  = blockIdx.z;
    const float* xb = x + (size_t)b * (3*64*256);

    const int lg = l >> 4;      // lane k-group
    const int li = l & 15;      // m/n index within tile
    char* const myw = sb + l*16;                 // write base: slot via immediate

    // ==== issue ALL sigma input loads up front (addresses depend only on j,t) ====
    float ps_[5][3];
#pragma unroll
    for (int s = 0; s < 5; ++s) {
        const int jp = path[j*5 + s];             // wave-uniform
        ps_[s][0] = xb[(0*64 + jp)*256 + t];
        ps_[s][1] = xb[(1*64 + jp)*256 + t];
        ps_[s][2] = xb[(2*64 + jp)*256 + t];
    }
    float pt_[7][3];
#pragma unroll
    for (int k = 0; k < 7; ++k) {
        const int idx  = j*7 + k;
        const int jsrc = idx & 63;
        const int tl   = idx >> 6;
        const int ts   = min(max(t + tl - 3, 0), 255);
        pt_[k][0] = xb[(0*64 + jsrc)*256 + ts];
        pt_[k][1] = xb[(1*64 + jsrc)*256 + ts];
        pt_[k][2] = xb[(2*64 + jsrc)*256 + ts];
    }

    unsigned S[42];

    // ---- sigma_s: init (d3=0), then 4 steps with d3 = 0.25 ----
    sig_init_h(S, cvtpk_h(ps_[0][0], ps_[0][1]), cvtpk_h(ps_[0][2], 0.f));
#pragma unroll
    for (int s = 1; s < 5; ++s) {
        const unsigned d01 = cvtpk_h(ps_[s][0]-ps_[s-1][0], ps_[s][1]-ps_[s-1][1]);
        const unsigned d23 = cvtpk_h(ps_[s][2]-ps_[s-1][2], 0.25f);
        sig_step_h(S, d01, d23);
    }
    // store sigma_s DIRECTLY (f16 pairs, linear k): slots 0..9 full, 10 half (+zeros)
    {
#pragma unroll
        for (int v = 0; v < 10; ++v) {
            uint32x4 w = { S[4*v], S[4*v+1], S[4*v+2], S[4*v+3] };
            *(uint32x4*)(myw + v*1024) = w;
        }
        uint32x4 w10 = { S[40], S[41], 0u, 0u }; *(uint32x4*)(myw + 10*1024) = w10;
    }
    __syncthreads();                                      // W->R: sigma_s ready

    // ---- GEMM1a FIRST: issue MFMAs, then sigma_t VALU runs in their shadow ----
    f32x4 acc[4][4];
#pragma unroll
    for (int to = 0; to < 4; ++to) {
        const f32x4 b0 = *(const f32x4*)(wsf + WS_B0 + to*16 + lg*4);
#pragma unroll
        for (int tt = 0; tt < 4; ++tt) acc[to][tt] = b0;
    }
    __builtin_amdgcn_s_setprio(1);
    {
#pragma unroll
        for (int s = 0; s < 3; ++s) {
            const int slot = (s*4+lg == 11) ? 8 : s*4+lg;   // slot-11 remap (A=0 there)
            f16x8 A0 = *(const f16x8*)(wsA1 + ((0*3+s)*4+0)*512 + l*8);
            f16x8 A1 = *(const f16x8*)(wsA1 + ((0*3+s)*4+1)*512 + l*8);
            f16x8 A2 = *(const f16x8*)(wsA1 + ((0*3+s)*4+2)*512 + l*8);
            f16x8 A3 = *(const f16x8*)(wsA1 + ((0*3+s)*4+3)*512 + l*8);
#pragma unroll
            for (int tt = 0; tt < 4; ++tt) {
                const f16x8 B = *(const f16x8*)(sb + slot*1024 + (tt*16+li)*16);
                acc[0][tt] = __builtin_amdgcn_mfma_f32_16x16x32_f16(A0, B, acc[0][tt], 0, 0, 0);
                acc[1][tt] = __builtin_amdgcn_mfma_f32_16x16x32_f16(A1, B, acc[1][tt], 0, 0, 0);
                acc[2][tt] = __builtin_amdgcn_mfma_f32_16x16x32_f16(A2, B, acc[2][tt], 0, 0, 0);
                acc[3][tt] = __builtin_amdgcn_mfma_f32_16x16x32_f16(A3, B, acc[3][tt], 0, 0, 0);
            }
        }
    }
    __builtin_amdgcn_s_setprio(0);

    // ---- sigma_t (VALU; overlaps GEMM1a's MFMA pipe) ----
    sig_init_h(S, cvtpk_h(pt_[0][0], pt_[0][1]), cvtpk_h(pt_[0][2], 0.f));
#pragma unroll
    for (int k = 1; k < 7; ++k) {
        const unsigned d01 = cvtpk_h(pt_[k][0]-pt_[k-1][0], pt_[k][1]-pt_[k-1][1]);
        const unsigned d23 = cvtpk_h(pt_[k][2]-pt_[k-1][2], (1.f/6.f));
        sig_step_h(S, d01, d23);
    }
    __syncthreads();                                      // R->W: done reading sigma_s

    // dump sigma_t state -> LDS slots 0..10
    {
#pragma unroll
        for (int v = 0; v < 10; ++v) {
            uint32x4 w = { S[4*v], S[4*v+1], S[4*v+2], S[4*v+3] };
            *(uint32x4*)(myw + v*1024) = w;
        }
        uint32x4 w10 = { S[40], S[41], 0u, 0u }; *(uint32x4*)(myw + 10*1024) = w10;
    }
    __syncthreads();                                      // W->R: sigma_t ready

    // conv window loads issued here (HBM latency hides under GEMM1b)
    float xv[9];
#pragma unroll
    for (int ci = 0; ci < 3; ++ci) {
        const float* xr = xb + (ci*64 + j)*256;
        xv[ci*3+0] = (t >= 1)   ? xr[t-1] : 0.f;
        xv[ci*3+1] = xr[t];
        xv[ci*3+2] = (t <= 254) ? xr[t+1] : 0.f;
    }

    // ---- GEMM1b: acc += A(h=1) * sigma_t ----
    __builtin_amdgcn_s_setprio(1);
    {
#pragma unroll
        for (int s = 0; s < 3; ++s) {
            const int slot = (s*4+lg == 11) ? 8 : s*4+lg;   // slot-11 remap (A=0 there)
            f16x8 A0 = *(const f16x8*)(wsA1 + ((1*3+s)*4+0)*512 + l*8);
            f16x8 A1 = *(const f16x8*)(wsA1 + ((1*3+s)*4+1)*512 + l*8);
            f16x8 A2 = *(const f16x8*)(wsA1 + ((1*3+s)*4+2)*512 + l*8);
            f16x8 A3 = *(const f16x8*)(wsA1 + ((1*3+s)*4+3)*512 + l*8);
#pragma unroll
            for (int tt = 0; tt < 4; ++tt) {
                const f16x8 B = *(const f16x8*)(sb + slot*1024 + (tt*16+li)*16);
                acc[0][tt] = __builtin_amdgcn_mfma_f32_16x16x32_f16(A0, B, acc[0][tt], 0, 0, 0);
                acc[1][tt] = __builtin_amdgcn_mfma_f32_16x16x32_f16(A1, B, acc[1][tt], 0, 0, 0);
                acc[2][tt] = __builtin_amdgcn_mfma_f32_16x16x32_f16(A2, B, acc[2][tt], 0, 0, 0);
                acc[3][tt] = __builtin_amdgcn_mfma_f32_16x16x32_f16(A3, B, acc[3][tt], 0, 0, 0);
            }
        }
    }
    __builtin_amdgcn_s_setprio(0);
    __syncthreads();                                      // R->W: done reading sigma_t

    // ---- ps pack: u_ps[row][o] = f16(relu(acc)) via f32 fmax + cvtpk, slots 0..7 ----
#pragma unroll
    for (int to = 0; to < 4; ++to) {
#pragma unroll
        for (int tt = 0; tt < 4; ++tt) {
            const unsigned w0 = cvtpk_h(fmaxf(acc[to][tt][0], 0.f), fmaxf(acc[to][tt][1], 0.f));
            const unsigned w1 = cvtpk_h(fmaxf(acc[to][tt][2], 0.f), fmaxf(acc[to][tt][3], 0.f));
            uint32x2 w = { w0, w1 };
            *(uint32x2*)(sb + (to*2+(lg>>1))*1024 + (tt*16+li)*16 + ((lg&1)<<3)) = w;
        }
    }
    // ---- xv pack (f16) -> slots 8,9 only (k=0..15; conv A=0 for k>=16) ----
    {
        unsigned xu[8];
        xu[0] = cvtpk_h(xv[0], xv[1]); xu[1] = cvtpk_h(xv[2], xv[3]);
        xu[2] = cvtpk_h(xv[4], xv[5]); xu[3] = cvtpk_h(xv[6], xv[7]);
        xu[4] = cvtpk_h(xv[8], 0.f);
#pragma unroll
        for (int i = 5; i < 8; ++i) xu[i] = 0u;
#pragma unroll
        for (int v = 0; v < 2; ++v) {
            uint32x4 w = { xu[4*v], xu[4*v+1], xu[4*v+2], xu[4*v+3] };
            *(uint32x4*)(myw + (8+v)*1024) = w;
        }
    }
    __syncthreads();                                      // W->R: u_ps + xv ready

    // ---- GEMM-conv via MFMA: acc = BC + Wc * xv  (B slots 8,9; lg>=2 remap, A=0) ----
#pragma unroll
    for (int to = 0; to < 4; ++to) {
        const f32x4 bc4 = *(const f32x4*)(wsf + WS_BC + to*16 + lg*4);
#pragma unroll
        for (int tt = 0; tt < 4; ++tt) acc[to][tt] = bc4;
    }
    __builtin_amdgcn_s_setprio(1);
    {
        const int cslot = 8 + (lg & 1);
        f16x8 A0 = *(const f16x8*)(wsA3 + 0*512 + l*8);
        f16x8 A1 = *(const f16x8*)(wsA3 + 1*512 + l*8);
        f16x8 A2 = *(const f16x8*)(wsA3 + 2*512 + l*8);
        f16x8 A3 = *(const f16x8*)(wsA3 + 3*512 + l*8);
#pragma unroll
        for (int tt = 0; tt < 4; ++tt) {
            const f16x8 B = *(const f16x8*)(sb + cslot*1024 + (tt*16+li)*16);
            acc[0][tt] = __builtin_amdgcn_mfma_f32_16x16x32_f16(A0, B, acc[0][tt], 0, 0, 0);
            acc[1][tt] = __builtin_amdgcn_mfma_f32_16x16x32_f16(A1, B, acc[1][tt], 0, 0, 0);
            acc[2][tt] = __builtin_amdgcn_mfma_f32_16x16x32_f16(A2, B, acc[2][tt], 0, 0, 0);
            acc[3][tt] = __builtin_amdgcn_mfma_f32_16x16x32_f16(A3, B, acc[3][tt], 0, 0, 0);
        }
    }
    __builtin_amdgcn_s_setprio(0);
    // relu-pack conv result to regs (same [row][o] mapping as ps pack)
    unsigned cu[32];
#pragma unroll
    for (int to = 0; to < 4; ++to)
#pragma unroll
        for (int tt = 0; tt < 4; ++tt) {
            cu[(to*4+tt)*2+0] = cvtpk_h(fmaxf(acc[to][tt][0], 0.f), fmaxf(acc[to][tt][1], 0.f));
            cu[(to*4+tt)*2+1] = cvtpk_h(fmaxf(acc[to][tt][2], 0.f), fmaxf(acc[to][tt][3], 0.f));
        }

    // ---- GEMM2-ps: acc = BF + Wf_hi^T u_ps  (A2 frags q = 8..15, slots 0..7) ----
#pragma unroll
    for (int to = 0; to < 4; ++to) {
        const f32x4 bf4 = *(const f32x4*)(wsf + WS_BF + to*16 + lg*4);
#pragma unroll
        for (int tt = 0; tt < 4; ++tt) acc[to][tt] = bf4;
    }
    __builtin_amdgcn_s_setprio(1);
    {
#pragma unroll
        for (int s = 0; s < 2; ++s) {
            f16x8 A0 = *(const f16x8*)(wsA2 + ((s+2)*4+0)*512 + l*8);
            f16x8 A1 = *(const f16x8*)(wsA2 + ((s+2)*4+1)*512 + l*8);
            f16x8 A2 = *(const f16x8*)(wsA2 + ((s+2)*4+2)*512 + l*8);
            f16x8 A3 = *(const f16x8*)(wsA2 + ((s+2)*4+3)*512 + l*8);
#pragma unroll
            for (int tt = 0; tt < 4; ++tt) {
                const f16x8 B = *(const f16x8*)(sb + (s*4+lg)*1024 + (tt*16+li)*16);
                acc[0][tt] = __builtin_amdgcn_mfma_f32_16x16x32_f16(A0, B, acc[0][tt], 0, 0, 0);
                acc[1][tt] = __builtin_amdgcn_mfma_f32_16x16x32_f16(A1, B, acc[1][tt], 0, 0, 0);
                acc[2][tt] = __builtin_amdgcn_mfma_f32_16x16x32_f16(A2, B, acc[2][tt], 0, 0, 0);
                acc[3][tt] = __builtin_amdgcn_mfma_f32_16x16x32_f16(A3, B, acc[3][tt], 0, 0, 0);
            }
        }
    }
    __builtin_amdgcn_s_setprio(0);
    __syncthreads();                                      // R->W: done reading u_ps

    // ---- conv store: u_conv[row][o] from cu -> slots 0..7 ----
#pragma unroll
    for (int to = 0; to < 4; ++to)
#pragma unroll
        for (int tt = 0; tt < 4; ++tt) {
            uint32x2 w = { cu[(to*4+tt)*2+0], cu[(to*4+tt)*2+1] };
            *(uint32x2*)(sb + (to*2+(lg>>1))*1024 + (tt*16+li)*16 + ((lg&1)<<3)) = w;
        }
    __syncthreads();                                      // W->R: u_conv ready

    // ---- GEMM2-conv: acc += Wf_lo^T u_conv  (A2 frags q = 0..7, slots 0..7) ----
    __builtin_amdgcn_s_setprio(1);
    {
#pragma unroll
        for (int s = 0; s < 2; ++s) {
            f16x8 A0 = *(const f16x8*)(wsA2 + (s*4+0)*512 + l*8);
            f16x8 A1 = *(const f16x8*)(wsA2 + (s*4+1)*512 + l*8);
            f16x8 A2 = *(const f16x8*)(wsA2 + (s*4+2)*512 + l*8);
            f16x8 A3 = *(const f16x8*)(wsA2 + (s*4+3)*512 + l*8);
#pragma unroll
            for (int tt = 0; tt < 4; ++tt) {
                const f16x8 B = *(const f16x8*)(sb + (s*4+lg)*1024 + (tt*16+li)*16);
                acc[0][tt] = __builtin_amdgcn_mfma_f32_16x16x32_f16(A0, B, acc[0][tt], 0, 0, 0);
                acc[1][tt] = __builtin_amdgcn_mfma_f32_16x16x32_f16(A1, B, acc[1][tt], 0, 0, 0);
                acc[2][tt] = __builtin_amdgcn_mfma_f32_16x16x32_f16(A2, B, acc[2][tt], 0, 0, 0);
                acc[3][tt] = __builtin_amdgcn_mfma_f32_16x16x32_f16(A3, B, acc[3][tt], 0, 0, 0);
            }
        }
    }
    __builtin_amdgcn_s_setprio(0);

    // ---- final epilogue: relu (bias already in C-init), store out[b][o][j][t] ----
#pragma unroll
    for (int to = 0; to < 4; ++to) {
#pragma unroll
        for (int tt = 0; tt < 4; ++tt) {
            const int tg = blockIdx.x*64 + tt*16 + li;
#pragma unroll
            for (int r = 0; r < 4; ++r) {
                const int o = to*16 + lg*4 + r;
                out[(((size_t)b*64 + o)*64 + j)*256 + tg] = fmaxf(acc[to][tt][r], 0.f);
            }
        }
    }
}

extern "C" void kernel_launch(void* const* d_in, const int* in_sizes, int n_in,
                              void* d_out, int out_size, void* d_ws, size_t ws_size,
                              hipStream_t stream)
{
    const float* x      = (const float*)d_in[0];
    const int*   path   = (const int*)  d_in[1];
    const float* W_ssig = (const float*)d_in[2];
    const float* b_ssig = (const float*)d_in[3];
    const float* W_tsig = (const float*)d_in[4];
    const float* b_tsig = (const float*)d_in[5];
    const float* W_raw  = (const float*)d_in[6];
    const float* b_raw  = (const float*)d_in[7];
    const float* W_ps   = (const float*)d_in[8];
    const float* b_ps   = (const float*)d_in[9];
    const float* W_fu   = (const float*)d_in[10];
    const float* b_fu   = (const float*)d_in[11];
    const float* g_raw  = (const float*)d_in[12];
    const float* be_raw = (const float*)d_in[13];
    const float* m_raw  = (const float*)d_in[14];
    const float* v_raw  = (const float*)d_in[15];
    const float* g_ps   = (const float*)d_in[16];
    const float* be_ps  = (const float*)d_in[17];
    const float* m_ps   = (const float*)d_in[18];
    const float* v_ps   = (const float*)d_in[19];
    const float* g_fu   = (const float*)d_in[20];
    const float* be_fu  = (const float*)d_in[21];
    const float* m_fu   = (const float*)d_in[22];
    const float* v_fu   = (const float*)d_in[23];
    float* out = (float*)d_out;

    float*          wsf  = (float*)d_ws;
    unsigned short* wsA1 = (unsigned short*)((char*)d_ws + 4096);
    unsigned short* wsA2 = (unsigned short*)((char*)d_ws + 28672);
    unsigned short* wsA3 = (unsigned short*)((char*)d_ws + 45056);

    stem_prep<<<45, 64, 0, stream>>>(W_ssig, b_ssig, W_tsig, b_tsig, W_raw, b_raw,
                                     W_ps, b_ps, W_fu, b_fu,
                                     g_raw, be_raw, m_raw, v_raw,
                                     g_ps, be_ps, m_ps, v_ps,
                                     g_fu, be_fu, m_fu, v_fu, wsf, wsA1, wsA2, wsA3);

    dim3 grid(4, 64, 32);   // (t-chunks, J, B)
    stem_main<<<grid, 64, 0, stream>>>(x, path, wsf, wsA1, wsA2, wsA3, out);
}